// Round 6
// baseline (747.050 us; speedup 1.0000x reference)
//
#include <hip/hip_runtime.h>
#include <stdint.h>

constexpr int kB = 8192;
constexpr int kD = 512;
constexpr int kH = 16384;
constexpr int kO = 1000;
constexpr int kNHB = kH / 256;          // 64 h-blocks (256-col granularity)
constexpr float kMargin = 0.12f;        // >= 2*e_max; e_max <= 2^-10*||x|| ~ 0.045

typedef _Float16 half8v __attribute__((ext_vector_type(8)));
typedef _Float16 half4v __attribute__((ext_vector_type(4)));
typedef float float4v __attribute__((ext_vector_type(4)));

#define VMW(n) asm volatile("s_waitcnt vmcnt(" #n ")" ::: "memory")

// ---------------------------------------------------------------------------
// ws layout (bytes):
//   OFF_XH  : f16 x_h [8192*512]               (8 MB)
//   OFF_WH  : f16 w_h [16384*512]              (16 MB)
//   OFF_W2  : f32 w2 [16384]                   (64 KB)
//   OFF_BT  : ulonglong2 blocktop [8192][64]   (8 MB)
//   OFF_GFT : f32 GfT [16384][1000]            (65.5 MB)
//   OFF_GRT : f32 GrT [16384][512]             (33.6 MB)
// ---------------------------------------------------------------------------
constexpr size_t OFF_XH  = 0;
constexpr size_t OFF_WH  = OFF_XH + (size_t)kB * kD * 2;
constexpr size_t OFF_W2  = OFF_WH + (size_t)kH * kD * 2;
constexpr size_t OFF_BT  = OFF_W2 + 65536;
constexpr size_t OFF_GFT = OFF_BT + (size_t)kB * kNHB * 16;
constexpr size_t OFF_GRT = OFF_GFT + (size_t)kH * kO * 4;
constexpr size_t WS_NEED = OFF_GRT + (size_t)kH * kD * 4;

__device__ inline unsigned long long packkey(float s, int h) {
    unsigned u = __float_as_uint(s);
    u ^= (u & 0x80000000u) ? 0xFFFFFFFFu : 0x80000000u;
    return ((unsigned long long)u << 32) | (unsigned)h;
}
__device__ inline float unpacks(unsigned long long k) {
    unsigned u = (unsigned)(k >> 32);
    u ^= (u & 0x80000000u) ? 0x80000000u : 0xFFFFFFFFu;
    return __uint_as_float(u);
}
__device__ inline unsigned long long shfl_xor_u64(unsigned long long v, int m) {
    unsigned lo = (unsigned)v, hi = (unsigned)(v >> 32);
    lo = __shfl_xor(lo, m, 64);
    hi = __shfl_xor(hi, m, 64);
    return ((unsigned long long)hi << 32) | lo;
}
__device__ inline unsigned long long u64min(unsigned long long a, unsigned long long b) {
    return a < b ? a : b;
}

template <typename T>
__device__ inline void gload_lds16(const T* g, T* l) {
    __builtin_amdgcn_global_load_lds(
        (const __attribute__((address_space(1))) uint32_t*)g,
        (__attribute__((address_space(3))) uint32_t*)l, 16, 0, 0);
}

// --------------------------- convert x: f32 -> f16 --------------------------
__global__ __launch_bounds__(256) void tof16_kernel(const float* __restrict__ src,
                                                    _Float16* __restrict__ dst) {
    size_t i = (size_t)blockIdx.x * 256 + threadIdx.x;   // 8 elems per thread
    const float4* s4 = reinterpret_cast<const float4*>(src);
    float4 a = s4[i * 2], b = s4[i * 2 + 1];
    half8v h = {(_Float16)a.x, (_Float16)a.y, (_Float16)a.z, (_Float16)a.w,
                (_Float16)b.x, (_Float16)b.y, (_Float16)b.z, (_Float16)b.w};
    *reinterpret_cast<half8v*>(dst + i * 8) = h;
}

// ------------------ convert W -> f16 + fused w2 (round-1 order) -------------
__global__ __launch_bounds__(256) void splitw_w2_kernel(const float* __restrict__ W,
                                                        _Float16* __restrict__ wh,
                                                        float* __restrict__ w2) {
    int lane = threadIdx.x & 63;
    int wv   = threadIdx.x >> 6;
    int row  = blockIdx.x * 4 + wv;
    const float4* Wr = reinterpret_cast<const float4*>(W + (size_t)row * kD);
    float s = 0.f;
#pragma unroll
    for (int i = 0; i < 2; ++i) {
        float4 v = Wr[lane + i * 64];
        s += v.x * v.x + v.y * v.y + v.z * v.z + v.w * v.w;
        half4v h = {(_Float16)v.x, (_Float16)v.y, (_Float16)v.z, (_Float16)v.w};
        *reinterpret_cast<half4v*>(wh + (size_t)row * kD + i * 256 + lane * 4) = h;
    }
#pragma unroll
    for (int off = 32; off; off >>= 1) s += __shfl_xor(s, off, 64);
    if (lane == 0) w2[row] = s;
}

// ------------------ 32x32 LDS-tiled transpose: src[R][C] -> dst[C][R] -------
__global__ __launch_bounds__(256) void transpose_kernel(const float* __restrict__ src,
                                                        float* __restrict__ dst,
                                                        int R, int C) {
    __shared__ float s[32][33];
    const int tx = threadIdx.x & 31;
    const int ty = threadIdx.x >> 5;       // 0..7
    const int c0 = blockIdx.x * 32;
    const int r0 = blockIdx.y * 32;
#pragma unroll
    for (int i = 0; i < 4; ++i) {
        int r = r0 + ty + i * 8;
        if (r < R) s[ty + i * 8][tx] = src[(size_t)r * C + c0 + tx];
    }
    __syncthreads();
#pragma unroll
    for (int i = 0; i < 4; ++i) {
        int c = c0 + ty + i * 8;
        if (r0 + tx < R) dst[(size_t)c * R + r0 + tx] = s[tx][ty + i * 8];
    }
}

// --------------------------- MFMA GEMM + per-block top2 ---------------------
// 256x256 tile, BK=32, 8 waves (2Mx4N, wave-tile 128x64), 4-deep circular LDS
// pipeline with counted vmcnt (one barrier per K-step, never vmcnt(0) in loop).
__global__ __launch_bounds__(512, 2) void gemm_argmin_mfma(
    const _Float16* __restrict__ xh, const _Float16* __restrict__ wh,
    const float* __restrict__ w2, ulonglong2* __restrict__ blocktop)
{
    __shared__ __align__(16) _Float16 smA[4][256 * 32];   // 16KB per buf
    __shared__ __align__(16) _Float16 smB[4][256 * 32];   // 16KB per buf

    const int tid  = threadIdx.x;
    const int lane = tid & 63;
    const int wv   = tid >> 6;          // 0..7
    const int wr   = wv >> 2;           // 0..1 (M)
    const int wc   = wv & 3;            // 0..3 (N)

    // XCD-aware swizzle (2048 % 8 == 0 -> bijective)
    int bid = blockIdx.x;
    int swz = (bid & 7) * (2048 / 8) + (bid >> 3);
    const int hb  = swz & 63;           // 64 h-blocks
    const int mb  = swz >> 6;           // 32 m-blocks
    const int bm0 = mb * 256, hn0 = hb * 256;

    float4v acc[8][4];
#pragma unroll
    for (int i = 0; i < 8; ++i)
#pragma unroll
        for (int j = 0; j < 4; ++j) acc[i][j] = (float4v){0.f, 0.f, 0.f, 0.f};

    // staging coords: one gload_lds16 stages 16 rows x 32 f16 (64 lanes x 16B)
    const int srow = lane >> 2;        // row within 16-row chunk
    const int sch  = lane & 3;         // dest 16B chunk within 64B row

    auto STAGEK = [&](int step) {      // full K-step stage: 2 A + 2 B gloads
        const int kt = step * 32;
        _Float16* dA = &smA[step & 3][0];
        _Float16* dB = &smB[step & 3][0];
#pragma unroll
        for (int h2 = 0; h2 < 2; ++h2) {
            const int r0 = wv * 32 + h2 * 16;            // wave-uniform
            const int r  = r0 + srow;
            const int cs = sch ^ ((r >> 1) & 3);         // pre-swizzled source chunk
            gload_lds16(xh + (size_t)(bm0 + r) * kD + kt + cs * 8, &dA[r0 * 32]);
            gload_lds16(wh + (size_t)(hn0 + r) * kD + kt + cs * 8, &dB[r0 * 32]);
        }
    };

    auto STEP = [&](int t, bool doStage) {
        const _Float16* As = &smA[t & 3][0];
        const _Float16* Bs = &smB[t & 3][0];
        half8v bfr[4];
#pragma unroll
        for (int j = 0; j < 4; ++j) {
            const int row = wc * 64 + j * 16 + (lane & 15);
            const int cs  = (lane >> 4) ^ ((row >> 1) & 3);
            bfr[j] = *reinterpret_cast<const half8v*>(&Bs[row * 32 + cs * 8]);
        }
        half8v afr[4];
#pragma unroll
        for (int i = 0; i < 4; ++i) {
            const int row = wr * 128 + i * 16 + (lane & 15);
            const int cs  = (lane >> 4) ^ ((row >> 1) & 3);
            afr[i] = *reinterpret_cast<const half8v*>(&As[row * 32 + cs * 8]);
        }
        if (doStage) {                 // A-half of stage(t+3)
            const int kt = (t + 3) * 32;
            _Float16* dA = &smA[(t + 3) & 3][0];
#pragma unroll
            for (int h2 = 0; h2 < 2; ++h2) {
                const int r0 = wv * 32 + h2 * 16;
                const int r  = r0 + srow;
                const int cs = sch ^ ((r >> 1) & 3);
                gload_lds16(xh + (size_t)(bm0 + r) * kD + kt + cs * 8, &dA[r0 * 32]);
            }
        }
        __builtin_amdgcn_s_setprio(1);
#pragma unroll
        for (int i = 0; i < 4; ++i)
#pragma unroll
            for (int j = 0; j < 4; ++j)
                acc[i][j] = __builtin_amdgcn_mfma_f32_16x16x32_f16(afr[i], bfr[j], acc[i][j], 0, 0, 0);
        __builtin_amdgcn_s_setprio(0);
        half8v afr2[4];
#pragma unroll
        for (int i = 0; i < 4; ++i) {
            const int row = wr * 128 + 64 + i * 16 + (lane & 15);
            const int cs  = (lane >> 4) ^ ((row >> 1) & 3);
            afr2[i] = *reinterpret_cast<const half8v*>(&As[row * 32 + cs * 8]);
        }
        if (doStage) {                 // B-half of stage(t+3)
            const int kt = (t + 3) * 32;
            _Float16* dB = &smB[(t + 3) & 3][0];
#pragma unroll
            for (int h2 = 0; h2 < 2; ++h2) {
                const int r0 = wv * 32 + h2 * 16;
                const int r  = r0 + srow;
                const int cs = sch ^ ((r >> 1) & 3);
                gload_lds16(wh + (size_t)(hn0 + r) * kD + kt + cs * 8, &dB[r0 * 32]);
            }
        }
        __builtin_amdgcn_s_setprio(1);
#pragma unroll
        for (int i = 0; i < 4; ++i)
#pragma unroll
            for (int j = 0; j < 4; ++j)
                acc[4 + i][j] = __builtin_amdgcn_mfma_f32_16x16x32_f16(afr2[i], bfr[j], acc[4 + i][j], 0, 0, 0);
        __builtin_amdgcn_s_setprio(0);
    };

    // prologue: stage steps 0,1,2 ; drain stage 0 ; barrier
    STAGEK(0); STAGEK(1); STAGEK(2);
    VMW(8);
    __builtin_amdgcn_s_barrier();

    // main loop: one barrier per K-step, counted vmcnt (3 stages in flight)
    for (int t = 0; t < 13; ++t) {
        STEP(t, true);                 // stages t+3 (3..15)
        VMW(8);                        // drain stage t+1
        __builtin_amdgcn_s_barrier();
    }
    STEP(13, false); VMW(4); __builtin_amdgcn_s_barrier();
    STEP(14, false); VMW(0); __builtin_amdgcn_s_barrier();
    STEP(15, false);
    __syncthreads();

    // ---------------- epilogue: per-row top2 over this block's 256 cols ------
    unsigned long long* top2p = reinterpret_cast<unsigned long long*>(&smA[0][0]); // [256][4][2]
    float w2v[4];
#pragma unroll
    for (int j = 0; j < 4; ++j) w2v[j] = w2[hn0 + wc * 64 + j * 16 + (lane & 15)];

#pragma unroll
    for (int i = 0; i < 8; ++i) {
#pragma unroll
        for (int r = 0; r < 4; ++r) {
            unsigned long long k1 = ~0ull, k2 = ~0ull;
#pragma unroll
            for (int j = 0; j < 4; ++j) {
                float s = fmaf(-2.f, acc[i][j][r], w2v[j]);
                unsigned long long key = packkey(s, hn0 + wc * 64 + j * 16 + (lane & 15));
                if (key < k1) { k2 = k1; k1 = key; }
                else if (key < k2) { k2 = key; }
            }
#pragma unroll
            for (int m = 1; m < 16; m <<= 1) {
                unsigned long long o1 = shfl_xor_u64(k1, m);
                unsigned long long o2 = shfl_xor_u64(k2, m);
                unsigned long long n1 = u64min(k1, o1);
                unsigned long long mx = k1 < o1 ? o1 : k1;
                unsigned long long mn = u64min(k2, o2);
                k1 = n1;
                k2 = u64min(mx, mn);
            }
            if ((lane & 15) == 0) {
                int rl = wr * 128 + i * 16 + (lane >> 4) * 4 + r;
                top2p[(rl * 4 + wc) * 2 + 0] = k1;
                top2p[(rl * 4 + wc) * 2 + 1] = k2;
            }
        }
    }
    __syncthreads();
    if (tid < 256) {
        unsigned long long m1 = ~0ull, m2 = ~0ull;
#pragma unroll
        for (int w = 0; w < 4; ++w) {
            unsigned long long a1 = top2p[(tid * 4 + w) * 2 + 0];
            unsigned long long a2 = top2p[(tid * 4 + w) * 2 + 1];
            if (a1 < m1) { m2 = u64min(m1, a2); m1 = a1; }
            else         { m2 = u64min(m2, a1); }
        }
        blocktop[(size_t)(bm0 + tid) * kNHB + hb] = (ulonglong2){m1, m2};
    }
}

// ---------------- finish: certify / exact-fp32 rescan + gather --------------
__global__ __launch_bounds__(256) void finish_kernel(
    const float* __restrict__ x, const float* __restrict__ W,
    const float* __restrict__ w2, const ulonglong2* __restrict__ blocktop,
    const float* __restrict__ Gf, const float* __restrict__ Gr,
    const float* __restrict__ GfT, const float* __restrict__ GrT,
    int useT, float* __restrict__ out)
{
    const int tid = threadIdx.x;
    const int b = blockIdx.x;
    __shared__ float xs[kD];
    __shared__ unsigned long long red[256];
    __shared__ unsigned long long sv1, sv2;
    __shared__ unsigned char cand[kNHB];

    if (tid < 128)
        reinterpret_cast<float4*>(xs)[tid] =
            reinterpret_cast<const float4*>(x + (size_t)b * kD)[tid];

    ulonglong2 t12;
    if (tid < kNHB) t12 = blocktop[(size_t)b * kNHB + tid];
    else            t12 = (ulonglong2){~0ull, ~0ull};

    red[tid] = (tid < kNHB) ? t12.x : ~0ull;
    __syncthreads();
    for (int s = 128; s > 0; s >>= 1) {
        if (tid < s) red[tid] = u64min(red[tid], red[tid + s]);
        __syncthreads();
    }
    if (tid == 0) sv1 = red[0];
    __syncthreads();
    const unsigned long long v1k = sv1;
    const float v1s = unpacks(v1k);
    const int b1hb = ((int)(unsigned)(v1k & 0xFFFFFFFFu)) >> 8;   // 256-col blocks

    red[tid] = (tid < kNHB) ? ((tid == b1hb) ? t12.y : t12.x) : ~0ull;
    __syncthreads();
    for (int s = 128; s > 0; s >>= 1) {
        if (tid < s) red[tid] = u64min(red[tid], red[tid + s]);
        __syncthreads();
    }
    if (tid == 0) sv2 = red[0];
    __syncthreads();
    const float v2s = unpacks(sv2);

    int idx;
    if (v2s - v1s > kMargin) {          // certified (block-uniform branch)
        idx = (int)(unsigned)(v1k & 0xFFFFFFFFu);
    } else {
        // uncertain: exact fp32 scan of candidate blocks (round-1 order)
        if (tid < kNHB) cand[tid] = (unpacks(t12.x) <= v1s + kMargin) ? 1 : 0;
        __syncthreads();
        unsigned long long bestk = ~0ull;
        for (int hb = 0; hb < kNHB; ++hb) {
            if (!cand[hb]) continue;
            int h = hb * 256 + tid;
            const float4* wr = reinterpret_cast<const float4*>(W + (size_t)h * kD);
            float dot = 0.f;
            for (int k = 0; k < kD / 4; ++k) {
                float4 wvv = wr[k];
                dot = fmaf(xs[k * 4 + 0], wvv.x, dot);
                dot = fmaf(xs[k * 4 + 1], wvv.y, dot);
                dot = fmaf(xs[k * 4 + 2], wvv.z, dot);
                dot = fmaf(xs[k * 4 + 3], wvv.w, dot);
            }
            float s = fmaf(-2.f, dot, w2[h]);
            bestk = u64min(bestk, packkey(s, h));
        }
        red[tid] = bestk;
        __syncthreads();
        for (int s = 128; s > 0; s >>= 1) {
            if (tid < s) red[tid] = u64min(red[tid], red[tid + s]);
            __syncthreads();
        }
        idx = (int)(unsigned)(red[0] & 0xFFFFFFFFu);
    }

    float* out0 = out;                            // (B, O)
    float* out1 = out + (size_t)kB * kO;          // (B, D)
    float* outw = out + (size_t)kB * (kO + kD);   // (B,)
    if (useT) {                                   // coalesced row gather
        const float4* gfr = reinterpret_cast<const float4*>(GfT + (size_t)idx * kO);
        float4* o0 = reinterpret_cast<float4*>(out0 + (size_t)b * kO);
        for (int o = tid; o < kO / 4; o += 256) o0[o] = gfr[o];
        const float4* grr = reinterpret_cast<const float4*>(GrT + (size_t)idx * kD);
        float4* o1 = reinterpret_cast<float4*>(out1 + (size_t)b * kD);
        if (tid < kD / 4) o1[tid] = grr[tid];
    } else {                                      // fallback: column gather
        for (int o = tid; o < kO; o += 256)
            out0[(size_t)b * kO + o] = Gf[(size_t)o * kH + idx];
        for (int d = tid; d < kD; d += 256)
            out1[(size_t)b * kD + d] = Gr[(size_t)d * kH + idx];
    }
    if (tid == 0) outw[b] = (float)idx;
}

extern "C" void kernel_launch(void* const* d_in, const int* in_sizes, int n_in,
                              void* d_out, int out_size, void* d_ws, size_t ws_size,
                              hipStream_t stream) {
    const float* x  = (const float*)d_in[0];
    const float* W  = (const float*)d_in[1];
    const float* Gf = (const float*)d_in[2];
    const float* Gr = (const float*)d_in[3];
    float* out = (float*)d_out;

    char* ws = (char*)d_ws;
    _Float16* xh = (_Float16*)(ws + OFF_XH);
    _Float16* wh = (_Float16*)(ws + OFF_WH);
    float* w2 = (float*)(ws + OFF_W2);
    ulonglong2* blocktop = (ulonglong2*)(ws + OFF_BT);
    float* GfT = (float*)(ws + OFF_GFT);
    float* GrT = (float*)(ws + OFF_GRT);
    const int useT = (ws_size >= WS_NEED) ? 1 : 0;

    hipLaunchKernelGGL(tof16_kernel, dim3(kB * kD / (256 * 8)), dim3(256), 0, stream, x, xh);
    hipLaunchKernelGGL(splitw_w2_kernel, dim3(kH / 4), dim3(256), 0, stream, W, wh, w2);
    if (useT) {
        hipLaunchKernelGGL(transpose_kernel, dim3(kH / 32, (kO + 31) / 32), dim3(256), 0, stream,
                           Gf, GfT, kO, kH);
        hipLaunchKernelGGL(transpose_kernel, dim3(kH / 32, kD / 32), dim3(256), 0, stream,
                           Gr, GrT, kD, kH);
    }
    hipLaunchKernelGGL(gemm_argmin_mfma, dim3(2048), dim3(512), 0, stream,
                       xh, wh, w2, blocktop);
    hipLaunchKernelGGL(finish_kernel, dim3(kB), dim3(256), 0, stream,
                       x, W, w2, blocktop, Gf, Gr, GfT, GrT, useT, out);
}

// Round 7
// 448.491 us; speedup vs baseline: 1.6657x; 1.6657x over previous
//
#include <hip/hip_runtime.h>
#include <stdint.h>

constexpr int kB = 8192;
constexpr int kD = 512;
constexpr int kH = 16384;
constexpr int kO = 1000;
constexpr int kNB64 = kH / 64;          // 256 candidate blocks of 64 cols
constexpr float kMargin = 0.12f;        // >= 2*E; E <= 2^-10*||x||_max ~ 0.052

typedef _Float16 half8v __attribute__((ext_vector_type(8)));
typedef _Float16 half4v __attribute__((ext_vector_type(4)));
typedef float float4v __attribute__((ext_vector_type(4)));

#define VMW(n) asm volatile("s_waitcnt vmcnt(" #n ")" ::: "memory")

// ---------------------------------------------------------------------------
// ws layout (bytes):
//   OFF_XH  : f16 x_h [8192*512]               (8 MB)
//   OFF_WH  : f16 w_h [16384*512]              (16 MB)
//   OFF_W2  : f32 w2 [16384]                   (64 KB)
//   OFF_BT  : ulonglong2 blocktop [8192][256]  (32 MB)
//   OFF_GFT : f32 GfT [16384][1000]            (65.5 MB)
//   OFF_GRT : f32 GrT [16384][512]             (33.6 MB)
// ---------------------------------------------------------------------------
constexpr size_t OFF_XH  = 0;
constexpr size_t OFF_WH  = OFF_XH + (size_t)kB * kD * 2;
constexpr size_t OFF_W2  = OFF_WH + (size_t)kH * kD * 2;
constexpr size_t OFF_BT  = OFF_W2 + 65536;
constexpr size_t OFF_GFT = OFF_BT + (size_t)kB * kNB64 * 16;
constexpr size_t OFF_GRT = OFF_GFT + (size_t)kH * kO * 4;
constexpr size_t WS_NEED = OFF_GRT + (size_t)kH * kD * 4;

__device__ inline unsigned long long packkey(float s, int h) {
    unsigned u = __float_as_uint(s);
    u ^= (u & 0x80000000u) ? 0xFFFFFFFFu : 0x80000000u;
    return ((unsigned long long)u << 32) | (unsigned)h;
}
__device__ inline float unpacks(unsigned long long k) {
    unsigned u = (unsigned)(k >> 32);
    u ^= (u & 0x80000000u) ? 0x80000000u : 0xFFFFFFFFu;
    return __uint_as_float(u);
}
__device__ inline unsigned long long shfl_xor_u64(unsigned long long v, int m) {
    unsigned lo = (unsigned)v, hi = (unsigned)(v >> 32);
    lo = __shfl_xor(lo, m, 64);
    hi = __shfl_xor(hi, m, 64);
    return ((unsigned long long)hi << 32) | lo;
}
__device__ inline unsigned long long u64min(unsigned long long a, unsigned long long b) {
    return a < b ? a : b;
}

template <typename T>
__device__ inline void gload_lds16(const T* g, T* l) {
    __builtin_amdgcn_global_load_lds(
        (const __attribute__((address_space(1))) uint32_t*)g,
        (__attribute__((address_space(3))) uint32_t*)l, 16, 0, 0);
}

// --------------------------- convert x: f32 -> f16 --------------------------
__global__ __launch_bounds__(256) void tof16_kernel(const float* __restrict__ src,
                                                    _Float16* __restrict__ dst) {
    size_t i = (size_t)blockIdx.x * 256 + threadIdx.x;   // 8 elems per thread
    const float4* s4 = reinterpret_cast<const float4*>(src);
    float4 a = s4[i * 2], b = s4[i * 2 + 1];
    half8v h = {(_Float16)a.x, (_Float16)a.y, (_Float16)a.z, (_Float16)a.w,
                (_Float16)b.x, (_Float16)b.y, (_Float16)b.z, (_Float16)b.w};
    *reinterpret_cast<half8v*>(dst + i * 8) = h;
}

// ------------------ convert W -> f16 + fused w2 (round-1 order) -------------
__global__ __launch_bounds__(256) void splitw_w2_kernel(const float* __restrict__ W,
                                                        _Float16* __restrict__ wh,
                                                        float* __restrict__ w2) {
    int lane = threadIdx.x & 63;
    int wv   = threadIdx.x >> 6;
    int row  = blockIdx.x * 4 + wv;
    const float4* Wr = reinterpret_cast<const float4*>(W + (size_t)row * kD);
    float s = 0.f;
#pragma unroll
    for (int i = 0; i < 2; ++i) {
        float4 v = Wr[lane + i * 64];
        s += v.x * v.x + v.y * v.y + v.z * v.z + v.w * v.w;
        half4v h = {(_Float16)v.x, (_Float16)v.y, (_Float16)v.z, (_Float16)v.w};
        *reinterpret_cast<half4v*>(wh + (size_t)row * kD + i * 256 + lane * 4) = h;
    }
#pragma unroll
    for (int off = 32; off; off >>= 1) s += __shfl_xor(s, off, 64);
    if (lane == 0) w2[row] = s;
}

// ------------------ 32x32 LDS-tiled transpose: src[R][C] -> dst[C][R] -------
__global__ __launch_bounds__(256) void transpose_kernel(const float* __restrict__ src,
                                                        float* __restrict__ dst,
                                                        int R, int C) {
    __shared__ float s[32][33];
    const int tx = threadIdx.x & 31;
    const int ty = threadIdx.x >> 5;       // 0..7
    const int c0 = blockIdx.x * 32;
    const int r0 = blockIdx.y * 32;
#pragma unroll
    for (int i = 0; i < 4; ++i) {
        int r = r0 + ty + i * 8;
        if (r < R) s[ty + i * 8][tx] = src[(size_t)r * C + c0 + tx];
    }
    __syncthreads();
#pragma unroll
    for (int i = 0; i < 4; ++i) {
        int c = c0 + ty + i * 8;
        if (r0 + tx < R) dst[(size_t)c * R + r0 + tx] = s[tx][ty + i * 8];
    }
}

// --------------------------- MFMA GEMM + per-64col top2 ---------------------
// 256x256 tile, BK=32, 8 waves (2Mx4N, wave-tile 128x64), 4-deep circular LDS
// pipeline with counted vmcnt (one barrier per K-step, never vmcnt(0) in loop).
// Epilogue: each wave stores per-row top2 over its OWN 64 cols (no merge).
__global__ __launch_bounds__(512, 2) void gemm_argmin_mfma(
    const _Float16* __restrict__ xh, const _Float16* __restrict__ wh,
    const float* __restrict__ w2, ulonglong2* __restrict__ blocktop)
{
    __shared__ __align__(16) _Float16 smA[4][256 * 32];   // 16KB per buf
    __shared__ __align__(16) _Float16 smB[4][256 * 32];   // 16KB per buf

    const int tid  = threadIdx.x;
    const int lane = tid & 63;
    const int wv   = tid >> 6;          // 0..7
    const int wr   = wv >> 2;           // 0..1 (M)
    const int wc   = wv & 3;            // 0..3 (N)

    // XCD-aware swizzle (2048 % 8 == 0 -> bijective)
    int bid = blockIdx.x;
    int swz = (bid & 7) * (2048 / 8) + (bid >> 3);
    const int hb  = swz & 63;           // 64 h-tiles
    const int mb  = swz >> 6;           // 32 m-tiles
    const int bm0 = mb * 256, hn0 = hb * 256;

    float4v acc[8][4];
#pragma unroll
    for (int i = 0; i < 8; ++i)
#pragma unroll
        for (int j = 0; j < 4; ++j) acc[i][j] = (float4v){0.f, 0.f, 0.f, 0.f};

    // staging coords: one gload_lds16 stages 16 rows x 32 f16 (64 lanes x 16B)
    const int srow = lane >> 2;        // row within 16-row chunk
    const int sch  = lane & 3;         // dest 16B chunk within 64B row

    auto STAGEK = [&](int step) {      // full K-step stage: 2 A + 2 B gloads
        const int kt = step * 32;
        _Float16* dA = &smA[step & 3][0];
        _Float16* dB = &smB[step & 3][0];
#pragma unroll
        for (int h2 = 0; h2 < 2; ++h2) {
            const int r0 = wv * 32 + h2 * 16;            // wave-uniform
            const int r  = r0 + srow;
            const int cs = sch ^ ((r >> 1) & 3);         // pre-swizzled source chunk
            gload_lds16(xh + (size_t)(bm0 + r) * kD + kt + cs * 8, &dA[r0 * 32]);
            gload_lds16(wh + (size_t)(hn0 + r) * kD + kt + cs * 8, &dB[r0 * 32]);
        }
    };

    auto STEP = [&](int t, bool doStage) {
        const _Float16* As = &smA[t & 3][0];
        const _Float16* Bs = &smB[t & 3][0];
        half8v bfr[4];
#pragma unroll
        for (int j = 0; j < 4; ++j) {
            const int row = wc * 64 + j * 16 + (lane & 15);
            const int cs  = (lane >> 4) ^ ((row >> 1) & 3);
            bfr[j] = *reinterpret_cast<const half8v*>(&Bs[row * 32 + cs * 8]);
        }
        half8v afr[4];
#pragma unroll
        for (int i = 0; i < 4; ++i) {
            const int row = wr * 128 + i * 16 + (lane & 15);
            const int cs  = (lane >> 4) ^ ((row >> 1) & 3);
            afr[i] = *reinterpret_cast<const half8v*>(&As[row * 32 + cs * 8]);
        }
        if (doStage) {                 // A-half of stage(t+3)
            const int kt = (t + 3) * 32;
            _Float16* dA = &smA[(t + 3) & 3][0];
#pragma unroll
            for (int h2 = 0; h2 < 2; ++h2) {
                const int r0 = wv * 32 + h2 * 16;
                const int r  = r0 + srow;
                const int cs = sch ^ ((r >> 1) & 3);
                gload_lds16(xh + (size_t)(bm0 + r) * kD + kt + cs * 8, &dA[r0 * 32]);
            }
        }
        __builtin_amdgcn_s_setprio(1);
#pragma unroll
        for (int i = 0; i < 4; ++i)
#pragma unroll
            for (int j = 0; j < 4; ++j)
                acc[i][j] = __builtin_amdgcn_mfma_f32_16x16x32_f16(afr[i], bfr[j], acc[i][j], 0, 0, 0);
        __builtin_amdgcn_s_setprio(0);
        half8v afr2[4];
#pragma unroll
        for (int i = 0; i < 4; ++i) {
            const int row = wr * 128 + 64 + i * 16 + (lane & 15);
            const int cs  = (lane >> 4) ^ ((row >> 1) & 3);
            afr2[i] = *reinterpret_cast<const half8v*>(&As[row * 32 + cs * 8]);
        }
        if (doStage) {                 // B-half of stage(t+3)
            const int kt = (t + 3) * 32;
            _Float16* dB = &smB[(t + 3) & 3][0];
#pragma unroll
            for (int h2 = 0; h2 < 2; ++h2) {
                const int r0 = wv * 32 + h2 * 16;
                const int r  = r0 + srow;
                const int cs = sch ^ ((r >> 1) & 3);
                gload_lds16(wh + (size_t)(hn0 + r) * kD + kt + cs * 8, &dB[r0 * 32]);
            }
        }
        __builtin_amdgcn_s_setprio(1);
#pragma unroll
        for (int i = 0; i < 4; ++i)
#pragma unroll
            for (int j = 0; j < 4; ++j)
                acc[4 + i][j] = __builtin_amdgcn_mfma_f32_16x16x32_f16(afr2[i], bfr[j], acc[4 + i][j], 0, 0, 0);
        __builtin_amdgcn_s_setprio(0);
    };

    // prologue: stage steps 0,1,2 ; drain stage 0 ; barrier
    STAGEK(0); STAGEK(1); STAGEK(2);
    VMW(8);
    __builtin_amdgcn_s_barrier();

    // main loop: one barrier per K-step, counted vmcnt (3 stages in flight)
    for (int t = 0; t < 13; ++t) {
        STEP(t, true);                 // stages t+3 (3..15)
        VMW(8);                        // drain stage t+1
        __builtin_amdgcn_s_barrier();
    }
    STEP(13, false); VMW(4); __builtin_amdgcn_s_barrier();
    STEP(14, false); VMW(0); __builtin_amdgcn_s_barrier();
    STEP(15, false);

    // ---- epilogue: per-row top2 over this wave's 64 cols, direct store -----
    float w2v[4];
#pragma unroll
    for (int j = 0; j < 4; ++j) w2v[j] = w2[hn0 + wc * 64 + j * 16 + (lane & 15)];

#pragma unroll
    for (int i = 0; i < 8; ++i) {
#pragma unroll
        for (int r = 0; r < 4; ++r) {
            unsigned long long k1 = ~0ull, k2 = ~0ull;
#pragma unroll
            for (int j = 0; j < 4; ++j) {
                float s = fmaf(-2.f, acc[i][j][r], w2v[j]);
                unsigned long long key = packkey(s, hn0 + wc * 64 + j * 16 + (lane & 15));
                if (key < k1) { k2 = k1; k1 = key; }
                else if (key < k2) { k2 = key; }
            }
#pragma unroll
            for (int m = 1; m < 16; m <<= 1) {
                unsigned long long o1 = shfl_xor_u64(k1, m);
                unsigned long long o2 = shfl_xor_u64(k2, m);
                unsigned long long n1 = u64min(k1, o1);
                unsigned long long mx = k1 < o1 ? o1 : k1;
                unsigned long long mn = u64min(k2, o2);
                k1 = n1;
                k2 = u64min(mx, mn);
            }
            if ((lane & 15) == 0) {
                int rl = wr * 128 + i * 16 + (lane >> 4) * 4 + r;
                blocktop[(size_t)(bm0 + rl) * kNB64 + hb * 4 + wc] = (ulonglong2){k1, k2};
            }
        }
    }
}

// ---------------- finish: certify / exact-fp32 rescan + gather --------------
__global__ __launch_bounds__(256) void finish_kernel(
    const float* __restrict__ x, const float* __restrict__ W,
    const float* __restrict__ w2, const ulonglong2* __restrict__ blocktop,
    const float* __restrict__ Gf, const float* __restrict__ Gr,
    const float* __restrict__ GfT, const float* __restrict__ GrT,
    int useTf, int useTr, float* __restrict__ out)
{
    const int tid = threadIdx.x;
    const int b = blockIdx.x;
    __shared__ float xs[kD];
    __shared__ unsigned long long red[256];
    __shared__ unsigned long long sv1, sv2;
    __shared__ int clist[kNB64];
    __shared__ int ccount;

    if (tid < 128)
        reinterpret_cast<float4*>(xs)[tid] =
            reinterpret_cast<const float4*>(x + (size_t)b * kD)[tid];
    if (tid == 0) ccount = 0;

    ulonglong2 t12 = blocktop[(size_t)b * kNB64 + tid];   // 256 threads = 256 blocks

    red[tid] = t12.x;
    __syncthreads();
    for (int s = 128; s > 0; s >>= 1) {
        if (tid < s) red[tid] = u64min(red[tid], red[tid + s]);
        __syncthreads();
    }
    if (tid == 0) sv1 = red[0];
    __syncthreads();
    const unsigned long long v1k = sv1;
    const float v1s = unpacks(v1k);
    const int b1hb = ((int)(unsigned)(v1k & 0xFFFFFFFFu)) >> 6;   // 64-col blocks

    red[tid] = (tid == b1hb) ? t12.y : t12.x;
    __syncthreads();
    for (int s = 128; s > 0; s >>= 1) {
        if (tid < s) red[tid] = u64min(red[tid], red[tid + s]);
        __syncthreads();
    }
    if (tid == 0) sv2 = red[0];
    __syncthreads();
    const float v2s = unpacks(sv2);

    int idx;
    if (v2s - v1s > kMargin) {          // certified (block-uniform branch)
        idx = (int)(unsigned)(v1k & 0xFFFFFFFFu);
    } else {
        // uncertain: compact candidate 64-col blocks, exact fp32 rescan,
        // one candidate block per wave, one h per lane.
        if (unpacks(t12.x) <= v1s + kMargin) {
            int p = atomicAdd(&ccount, 1);
            clist[p] = tid;
        }
        __syncthreads();
        const int nc = ccount;
        const int wvf = tid >> 6, lnf = tid & 63;
        unsigned long long bestk = ~0ull;
        for (int c = wvf; c < nc; c += 4) {
            int h = clist[c] * 64 + lnf;
            const float4* wr = reinterpret_cast<const float4*>(W + (size_t)h * kD);
            float dot = 0.f;
            for (int k = 0; k < kD / 4; ++k) {
                float4 wvv = wr[k];
                dot = fmaf(xs[k * 4 + 0], wvv.x, dot);
                dot = fmaf(xs[k * 4 + 1], wvv.y, dot);
                dot = fmaf(xs[k * 4 + 2], wvv.z, dot);
                dot = fmaf(xs[k * 4 + 3], wvv.w, dot);
            }
            float s = fmaf(-2.f, dot, w2[h]);
            bestk = u64min(bestk, packkey(s, h));
        }
        red[tid] = bestk;
        __syncthreads();
        for (int s = 128; s > 0; s >>= 1) {
            if (tid < s) red[tid] = u64min(red[tid], red[tid + s]);
            __syncthreads();
        }
        idx = (int)(unsigned)(red[0] & 0xFFFFFFFFu);
    }

    float* out0 = out;                            // (B, O)
    float* out1 = out + (size_t)kB * kO;          // (B, D)
    float* outw = out + (size_t)kB * (kO + kD);   // (B,)
    if (useTf) {                                  // coalesced row gather
        const float4* gfr = reinterpret_cast<const float4*>(GfT + (size_t)idx * kO);
        float4* o0 = reinterpret_cast<float4*>(out0 + (size_t)b * kO);
        for (int o = tid; o < kO / 4; o += 256) o0[o] = gfr[o];
    } else {
        for (int o = tid; o < kO; o += 256)
            out0[(size_t)b * kO + o] = Gf[(size_t)o * kH + idx];
    }
    if (useTr) {
        const float4* grr = reinterpret_cast<const float4*>(GrT + (size_t)idx * kD);
        float4* o1 = reinterpret_cast<float4*>(out1 + (size_t)b * kD);
        if (tid < kD / 4) o1[tid] = grr[tid];
    } else {
        for (int d = tid; d < kD; d += 256)
            out1[(size_t)b * kD + d] = Gr[(size_t)d * kH + idx];
    }
    if (tid == 0) outw[b] = (float)idx;
}

extern "C" void kernel_launch(void* const* d_in, const int* in_sizes, int n_in,
                              void* d_out, int out_size, void* d_ws, size_t ws_size,
                              hipStream_t stream) {
    const float* x  = (const float*)d_in[0];
    const float* W  = (const float*)d_in[1];
    const float* Gf = (const float*)d_in[2];
    const float* Gr = (const float*)d_in[3];
    float* out = (float*)d_out;

    char* ws = (char*)d_ws;
    _Float16* xh = (_Float16*)(ws + OFF_XH);
    _Float16* wh = (_Float16*)(ws + OFF_WH);
    float* w2 = (float*)(ws + OFF_W2);
    ulonglong2* blocktop = (ulonglong2*)(ws + OFF_BT);
    float* GfT = (float*)(ws + OFF_GFT);
    float* GrT = (float*)(ws + OFF_GRT);
    const int useTf = (ws_size >= OFF_GRT) ? 1 : 0;
    const int useTr = (ws_size >= WS_NEED) ? 1 : 0;

    hipLaunchKernelGGL(tof16_kernel, dim3(kB * kD / (256 * 8)), dim3(256), 0, stream, x, xh);
    hipLaunchKernelGGL(splitw_w2_kernel, dim3(kH / 4), dim3(256), 0, stream, W, wh, w2);
    if (useTf)
        hipLaunchKernelGGL(transpose_kernel, dim3(kH / 32, (kO + 31) / 32), dim3(256), 0, stream,
                           Gf, GfT, kO, kH);
    if (useTr)
        hipLaunchKernelGGL(transpose_kernel, dim3(kH / 32, kD / 32), dim3(256), 0, stream,
                           Gr, GrT, kD, kH);
    hipLaunchKernelGGL(gemm_argmin_mfma, dim3(2048), dim3(512), 0, stream,
                       xh, wh, w2, blocktop);
    hipLaunchKernelGGL(finish_kernel, dim3(kB), dim3(256), 0, stream,
                       x, W, w2, blocktop, Gf, Gr, GfT, GrT, useTf, useTr, out);
}

// Round 8
// 431.742 us; speedup vs baseline: 1.7303x; 1.0388x over previous
//
#include <hip/hip_runtime.h>
#include <stdint.h>

constexpr int kB = 8192;
constexpr int kD = 512;
constexpr int kH = 16384;
constexpr int kO = 1000;
constexpr int kNB64 = kH / 64;          // 256 candidate blocks of 64 cols
constexpr float kMargin = 0.12f;        // >= 2*E; E <= 2^-10*||x||_max ~ 0.052

typedef _Float16 half8v __attribute__((ext_vector_type(8)));
typedef _Float16 half4v __attribute__((ext_vector_type(4)));
typedef float float4v __attribute__((ext_vector_type(4)));

#define VMW(n) asm volatile("s_waitcnt vmcnt(" #n ")" ::: "memory")

// ---------------------------------------------------------------------------
// ws layout (bytes):
//   OFF_XH  : f16 x_h [8192*512]               (8 MB)
//   OFF_WH  : f16 w_h [16384*512]              (16 MB)
//   OFF_W2  : f32 w2 [16384]                   (64 KB)
//   OFF_BT  : ulonglong2 blocktop [8192][256]  (32 MB)
//   OFF_GFT : f32 GfT [16384][1000]            (65.5 MB)
//   OFF_GRT : f32 GrT [16384][512]             (33.6 MB)
// ---------------------------------------------------------------------------
constexpr size_t OFF_XH  = 0;
constexpr size_t OFF_WH  = OFF_XH + (size_t)kB * kD * 2;
constexpr size_t OFF_W2  = OFF_WH + (size_t)kH * kD * 2;
constexpr size_t OFF_BT  = OFF_W2 + 65536;
constexpr size_t OFF_GFT = OFF_BT + (size_t)kB * kNB64 * 16;
constexpr size_t OFF_GRT = OFF_GFT + (size_t)kH * kO * 4;
constexpr size_t WS_NEED = OFF_GRT + (size_t)kH * kD * 4;

__device__ inline unsigned long long packkey(float s, int h) {
    unsigned u = __float_as_uint(s);
    u ^= (u & 0x80000000u) ? 0xFFFFFFFFu : 0x80000000u;
    return ((unsigned long long)u << 32) | (unsigned)h;
}
__device__ inline float unpacks(unsigned long long k) {
    unsigned u = (unsigned)(k >> 32);
    u ^= (u & 0x80000000u) ? 0x80000000u : 0xFFFFFFFFu;
    return __uint_as_float(u);
}
__device__ inline unsigned long long shfl_xor_u64(unsigned long long v, int m) {
    unsigned lo = (unsigned)v, hi = (unsigned)(v >> 32);
    lo = __shfl_xor(lo, m, 64);
    hi = __shfl_xor(hi, m, 64);
    return ((unsigned long long)hi << 32) | lo;
}
__device__ inline unsigned long long u64min(unsigned long long a, unsigned long long b) {
    return a < b ? a : b;
}

template <typename T>
__device__ inline void gload_lds16(const T* g, T* l) {
    __builtin_amdgcn_global_load_lds(
        (const __attribute__((address_space(1))) uint32_t*)g,
        (__attribute__((address_space(3))) uint32_t*)l, 16, 0, 0);
}

// --------------------------- convert x: f32 -> f16 --------------------------
__global__ __launch_bounds__(256) void tof16_kernel(const float* __restrict__ src,
                                                    _Float16* __restrict__ dst) {
    size_t i = (size_t)blockIdx.x * 256 + threadIdx.x;   // 8 elems per thread
    const float4* s4 = reinterpret_cast<const float4*>(src);
    float4 a = s4[i * 2], b = s4[i * 2 + 1];
    half8v h = {(_Float16)a.x, (_Float16)a.y, (_Float16)a.z, (_Float16)a.w,
                (_Float16)b.x, (_Float16)b.y, (_Float16)b.z, (_Float16)b.w};
    *reinterpret_cast<half8v*>(dst + i * 8) = h;
}

// ------------------ convert W -> f16 + fused w2 (round-1 order) -------------
__global__ __launch_bounds__(256) void splitw_w2_kernel(const float* __restrict__ W,
                                                        _Float16* __restrict__ wh,
                                                        float* __restrict__ w2) {
    int lane = threadIdx.x & 63;
    int wv   = threadIdx.x >> 6;
    int row  = blockIdx.x * 4 + wv;
    const float4* Wr = reinterpret_cast<const float4*>(W + (size_t)row * kD);
    float s = 0.f;
#pragma unroll
    for (int i = 0; i < 2; ++i) {
        float4 v = Wr[lane + i * 64];
        s += v.x * v.x + v.y * v.y + v.z * v.z + v.w * v.w;
        half4v h = {(_Float16)v.x, (_Float16)v.y, (_Float16)v.z, (_Float16)v.w};
        *reinterpret_cast<half4v*>(wh + (size_t)row * kD + i * 256 + lane * 4) = h;
    }
#pragma unroll
    for (int off = 32; off; off >>= 1) s += __shfl_xor(s, off, 64);
    if (lane == 0) w2[row] = s;
}

// ------------------ 32x32 LDS-tiled transpose: src[R][C] -> dst[C][R] -------
__global__ __launch_bounds__(256) void transpose_kernel(const float* __restrict__ src,
                                                        float* __restrict__ dst,
                                                        int R, int C) {
    __shared__ float s[32][33];
    const int tx = threadIdx.x & 31;
    const int ty = threadIdx.x >> 5;       // 0..7
    const int c0 = blockIdx.x * 32;
    const int r0 = blockIdx.y * 32;
#pragma unroll
    for (int i = 0; i < 4; ++i) {
        int r = r0 + ty + i * 8;
        if (r < R) s[ty + i * 8][tx] = src[(size_t)r * C + c0 + tx];
    }
    __syncthreads();
#pragma unroll
    for (int i = 0; i < 4; ++i) {
        int c = c0 + ty + i * 8;
        if (r0 + tx < R) dst[(size_t)c * R + r0 + tx] = s[tx][ty + i * 8];
    }
}

// --------------------------- MFMA GEMM + per-64col top2 ---------------------
// 256x256 tile, BK=64 (two K=32 halves), 8 waves (2Mx4N, wave-tile 128x64).
// 8-phase-style schedule: per phase {8 ds_read_b128 (one (kk,mh) quadrant) ||
// stage 1 half-tile (2 gload_lds, stage-ahead=5) -> barrier -> lgkmcnt(0) ->
// setprio(1) 16 MFMA setprio(0) -> [VMW(6) at kk-transitions] -> barrier}.
// LDS: 2 buffers x 4 half-regions [A-K0,B-K0,A-K1,B-K1] x 16KB = 128KB.
__global__ __launch_bounds__(512, 2) void gemm_argmin_mfma(
    const _Float16* __restrict__ xh, const _Float16* __restrict__ wh,
    const float* __restrict__ w2, ulonglong2* __restrict__ blocktop)
{
    __shared__ __align__(16) _Float16 sm[65536];   // 128 KB

    const int tid  = threadIdx.x;
    const int lane = tid & 63;
    const int wv   = tid >> 6;          // 0..7
    const int wr   = wv >> 2;           // 0..1 (M)
    const int wc   = wv & 3;            // 0..3 (N)

    // XCD-aware swizzle (2048 % 8 == 0 -> bijective)
    int bid = blockIdx.x;
    int swz = (bid & 7) * (2048 / 8) + (bid >> 3);
    const int hb  = swz & 63;           // 64 h-tiles
    const int mb  = swz >> 6;           // 32 m-tiles
    const int bm0 = mb * 256, hn0 = hb * 256;

    float4v acc[8][4];
#pragma unroll
    for (int i = 0; i < 8; ++i)
#pragma unroll
        for (int j = 0; j < 4; ++j) acc[i][j] = (float4v){0.f, 0.f, 0.f, 0.f};

    // ---- stage one 16KB half-tile h (global half index 0..31) --------------
    // h = 4*T + jp ; jp: 0=A-K0, 1=B-K0, 2=A-K1, 3=B-K1 of K-tile T.
    auto STAGEH = [&](int h) {
        const int T2 = h >> 2, jp = h & 3;
        const int kk = jp >> 1, isB = jp & 1;
        const int kt = T2 * 64 + kk * 32;
        _Float16* dst0 = &sm[(((T2 & 1) << 2) | jp) * 8192 + wv * 512];
#pragma unroll
        for (int l = 0; l < 2; ++l) {
            const int idx = l * 512 + tid;        // 0..1023
            const int r = idx >> 2, c = idx & 3;  // row 0..255, chunk 0..3
            const int sc = c ^ ((r >> 1) & 3);    // pre-swizzled source chunk
            const _Float16* src =
                (isB ? wh + (size_t)(hn0 + r) * kD : xh + (size_t)(bm0 + r) * kD)
                + kt + sc * 8;
            gload_lds16(src, dst0 + l * 4096);
        }
    };

    // ---- one phase: quadrant (kk, mh) of buffer buf; stage half h ----------
    auto PH = [&](int buf, int kk, int mh, int h) {
        const int fbase = buf * 32768 + kk * 16384;   // A region; B at +8192
        half8v bfr[4], afr[4];
#pragma unroll
        for (int jn = 0; jn < 4; ++jn) {
            const int r = wc * 64 + jn * 16 + (lane & 15);
            const int cs = (lane >> 4) ^ ((r >> 1) & 3);
            bfr[jn] = *reinterpret_cast<const half8v*>(&sm[fbase + 8192 + r * 32 + cs * 8]);
        }
#pragma unroll
        for (int im = 0; im < 4; ++im) {
            const int r = wr * 128 + mh * 64 + im * 16 + (lane & 15);
            const int cs = (lane >> 4) ^ ((r >> 1) & 3);
            afr[im] = *reinterpret_cast<const half8v*>(&sm[fbase + r * 32 + cs * 8]);
        }
        if (h < 32) STAGEH(h);
        __builtin_amdgcn_s_barrier();
        asm volatile("s_waitcnt lgkmcnt(0)" ::: "memory");
        __builtin_amdgcn_sched_barrier(0);
        __builtin_amdgcn_s_setprio(1);
#pragma unroll
        for (int im = 0; im < 4; ++im)
#pragma unroll
            for (int jn = 0; jn < 4; ++jn)
                acc[mh * 4 + im][jn] =
                    __builtin_amdgcn_mfma_f32_16x16x32_f16(afr[im], bfr[jn],
                                                           acc[mh * 4 + im][jn], 0, 0, 0);
        __builtin_amdgcn_s_setprio(0);
    };

    // ---- prologue: stage halves 0..4, wait for halves 0,1, sync ------------
    STAGEH(0); STAGEH(1); STAGEH(2); STAGEH(3); STAGEH(4);
    VMW(6);
    __builtin_amdgcn_s_barrier();

    // ---- main loop: K-tiles 0..5 (stage h = p+5; VMW(6) at kk transitions) -
    for (int T = 0; T < 6; ++T) {
        const int buf = T & 1;
        const int p0 = 4 * T;
        PH(buf, 0, 0, p0 + 5);          __builtin_amdgcn_s_barrier();
        PH(buf, 0, 1, p0 + 6); VMW(6);  __builtin_amdgcn_s_barrier();
        PH(buf, 1, 0, p0 + 7);          __builtin_amdgcn_s_barrier();
        PH(buf, 1, 1, p0 + 8); VMW(6);  __builtin_amdgcn_s_barrier();
    }
    // ---- K-tile 6 (last stages h=29..31) -----------------------------------
    PH(0, 0, 0, 29);          __builtin_amdgcn_s_barrier();
    PH(0, 0, 1, 30); VMW(6);  __builtin_amdgcn_s_barrier();
    PH(0, 1, 0, 31);          __builtin_amdgcn_s_barrier();
    PH(0, 1, 1, 33); VMW(4);  __builtin_amdgcn_s_barrier();
    // ---- K-tile 7 (no stages; drain) ---------------------------------------
    PH(1, 0, 0, 33);          __builtin_amdgcn_s_barrier();
    PH(1, 0, 1, 33); VMW(0);  __builtin_amdgcn_s_barrier();
    PH(1, 1, 0, 33);          __builtin_amdgcn_s_barrier();
    PH(1, 1, 1, 33);

    // ---- epilogue: per-row top2 over this wave's 64 cols, direct store -----
    float w2v[4];
#pragma unroll
    for (int j = 0; j < 4; ++j) w2v[j] = w2[hn0 + wc * 64 + j * 16 + (lane & 15)];

#pragma unroll
    for (int i = 0; i < 8; ++i) {
#pragma unroll
        for (int r = 0; r < 4; ++r) {
            unsigned long long k1 = ~0ull, k2 = ~0ull;
#pragma unroll
            for (int j = 0; j < 4; ++j) {
                float s = fmaf(-2.f, acc[i][j][r], w2v[j]);
                unsigned long long key = packkey(s, hn0 + wc * 64 + j * 16 + (lane & 15));
                if (key < k1) { k2 = k1; k1 = key; }
                else if (key < k2) { k2 = key; }
            }
#pragma unroll
            for (int m = 1; m < 16; m <<= 1) {
                unsigned long long o1 = shfl_xor_u64(k1, m);
                unsigned long long o2 = shfl_xor_u64(k2, m);
                unsigned long long n1 = u64min(k1, o1);
                unsigned long long mx = k1 < o1 ? o1 : k1;
                unsigned long long mn = u64min(k2, o2);
                k1 = n1;
                k2 = u64min(mx, mn);
            }
            if ((lane & 15) == 0) {
                int rl = wr * 128 + i * 16 + (lane >> 4) * 4 + r;
                blocktop[(size_t)(bm0 + rl) * kNB64 + hb * 4 + wc] = (ulonglong2){k1, k2};
            }
        }
    }
}

// ---------------- finish: certify / exact-fp32 rescan + gather --------------
__global__ __launch_bounds__(256) void finish_kernel(
    const float* __restrict__ x, const float* __restrict__ W,
    const float* __restrict__ w2, const ulonglong2* __restrict__ blocktop,
    const float* __restrict__ Gf, const float* __restrict__ Gr,
    const float* __restrict__ GfT, const float* __restrict__ GrT,
    int useTf, int useTr, float* __restrict__ out)
{
    const int tid = threadIdx.x;
    const int b = blockIdx.x;
    __shared__ float xs[kD];
    __shared__ unsigned long long red[256];
    __shared__ unsigned long long sv1, sv2;
    __shared__ int clist[kNB64];
    __shared__ int ccount;

    if (tid < 128)
        reinterpret_cast<float4*>(xs)[tid] =
            reinterpret_cast<const float4*>(x + (size_t)b * kD)[tid];
    if (tid == 0) ccount = 0;

    ulonglong2 t12 = blocktop[(size_t)b * kNB64 + tid];   // 256 threads = 256 blocks

    red[tid] = t12.x;
    __syncthreads();
    for (int s = 128; s > 0; s >>= 1) {
        if (tid < s) red[tid] = u64min(red[tid], red[tid + s]);
        __syncthreads();
    }
    if (tid == 0) sv1 = red[0];
    __syncthreads();
    const unsigned long long v1k = sv1;
    const float v1s = unpacks(v1k);
    const int b1hb = ((int)(unsigned)(v1k & 0xFFFFFFFFu)) >> 6;   // 64-col blocks

    red[tid] = (tid == b1hb) ? t12.y : t12.x;
    __syncthreads();
    for (int s = 128; s > 0; s >>= 1) {
        if (tid < s) red[tid] = u64min(red[tid], red[tid + s]);
        __syncthreads();
    }
    if (tid == 0) sv2 = red[0];
    __syncthreads();
    const float v2s = unpacks(sv2);

    int idx;
    if (v2s - v1s > kMargin) {          // certified (block-uniform branch)
        idx = (int)(unsigned)(v1k & 0xFFFFFFFFu);
    } else {
        // uncertain: compact candidate 64-col blocks, exact fp32 rescan,
        // one candidate block per wave, one h per lane.
        if (unpacks(t12.x) <= v1s + kMargin) {
            int p = atomicAdd(&ccount, 1);
            clist[p] = tid;
        }
        __syncthreads();
        const int nc = ccount;
        const int wvf = tid >> 6, lnf = tid & 63;
        unsigned long long bestk = ~0ull;
        for (int c = wvf; c < nc; c += 4) {
            int h = clist[c] * 64 + lnf;
            const float4* wr = reinterpret_cast<const float4*>(W + (size_t)h * kD);
            float dot = 0.f;
            for (int k = 0; k < kD / 4; ++k) {
                float4 wvv = wr[k];
                dot = fmaf(xs[k * 4 + 0], wvv.x, dot);
                dot = fmaf(xs[k * 4 + 1], wvv.y, dot);
                dot = fmaf(xs[k * 4 + 2], wvv.z, dot);
                dot = fmaf(xs[k * 4 + 3], wvv.w, dot);
            }
            float s = fmaf(-2.f, dot, w2[h]);
            bestk = u64min(bestk, packkey(s, h));
        }
        red[tid] = bestk;
        __syncthreads();
        for (int s = 128; s > 0; s >>= 1) {
            if (tid < s) red[tid] = u64min(red[tid], red[tid + s]);
            __syncthreads();
        }
        idx = (int)(unsigned)(red[0] & 0xFFFFFFFFu);
    }

    float* out0 = out;                            // (B, O)
    float* out1 = out + (size_t)kB * kO;          // (B, D)
    float* outw = out + (size_t)kB * (kO + kD);   // (B,)
    if (useTf) {                                  // coalesced row gather
        const float4* gfr = reinterpret_cast<const float4*>(GfT + (size_t)idx * kO);
        float4* o0 = reinterpret_cast<float4*>(out0 + (size_t)b * kO);
        for (int o = tid; o < kO / 4; o += 256) o0[o] = gfr[o];
    } else {
        for (int o = tid; o < kO; o += 256)
            out0[(size_t)b * kO + o] = Gf[(size_t)o * kH + idx];
    }
    if (useTr) {
        const float4* grr = reinterpret_cast<const float4*>(GrT + (size_t)idx * kD);
        float4* o1 = reinterpret_cast<float4*>(out1 + (size_t)b * kD);
        if (tid < kD / 4) o1[tid] = grr[tid];
    } else {
        for (int d = tid; d < kD; d += 256)
            out1[(size_t)b * kD + d] = Gr[(size_t)d * kH + idx];
    }
    if (tid == 0) outw[b] = (float)idx;
}

extern "C" void kernel_launch(void* const* d_in, const int* in_sizes, int n_in,
                              void* d_out, int out_size, void* d_ws, size_t ws_size,
                              hipStream_t stream) {
    const float* x  = (const float*)d_in[0];
    const float* W  = (const float*)d_in[1];
    const float* Gf = (const float*)d_in[2];
    const float* Gr = (const float*)d_in[3];
    float* out = (float*)d_out;

    char* ws = (char*)d_ws;
    _Float16* xh = (_Float16*)(ws + OFF_XH);
    _Float16* wh = (_Float16*)(ws + OFF_WH);
    float* w2 = (float*)(ws + OFF_W2);
    ulonglong2* blocktop = (ulonglong2*)(ws + OFF_BT);
    float* GfT = (float*)(ws + OFF_GFT);
    float* GrT = (float*)(ws + OFF_GRT);
    const int useTf = (ws_size >= OFF_GRT) ? 1 : 0;
    const int useTr = (ws_size >= WS_NEED) ? 1 : 0;

    hipLaunchKernelGGL(tof16_kernel, dim3(kB * kD / (256 * 8)), dim3(256), 0, stream, x, xh);
    hipLaunchKernelGGL(splitw_w2_kernel, dim3(kH / 4), dim3(256), 0, stream, W, wh, w2);
    if (useTf)
        hipLaunchKernelGGL(transpose_kernel, dim3(kH / 32, (kO + 31) / 32), dim3(256), 0, stream,
                           Gf, GfT, kO, kH);
    if (useTr)
        hipLaunchKernelGGL(transpose_kernel, dim3(kH / 32, kD / 32), dim3(256), 0, stream,
                           Gr, GrT, kD, kH);
    hipLaunchKernelGGL(gemm_argmin_mfma, dim3(2048), dim3(512), 0, stream,
                       xh, wh, w2, blocktop);
    hipLaunchKernelGGL(finish_kernel, dim3(kB), dim3(256), 0, stream,
                       x, W, w2, blocktop, Gf, Gr, GfT, GrT, useTf, useTr, out);
}